// Round 1
// baseline (94.631 us; speedup 1.0000x reference)
//
#include <hip/hip_runtime.h>
#include <math.h>

#define NN 512   // nodes
#define MM 512   // edges
#define DD 128   // emb dim
#define HH 256   // hidden

// ws layout (float offsets)
#define WS_SUMS 0
#define WS_CNT  (MM * DD)          // 65536
#define WS_A    (WS_CNT + MM)      // 66048:  A[n][h] = X[n,:].W1[h,0:128]
#define WS_C    (WS_A + NN * HH)   // 197120: C[m][h] = eX[m,:].W1[h,128:256] + b1[h]

// ---------------------------------------------------------------- scatter-sum
__global__ __launch_bounds__(256) void k_scatter(
    const float* __restrict__ X, const int* __restrict__ V,
    const int* __restrict__ E, float* __restrict__ sums,
    float* __restrict__ cnt)
{
    int tid = blockIdx.x * 256 + threadIdx.x;   // over 8192*128
    int i = tid >> 7;
    int d = tid & 127;
    int v = V[i];
    int e = E[i];
    atomicAdd(&sums[e * DD + d], X[v * DD + d]);
    if (d == 0) atomicAdd(&cnt[e], 1.0f);
}

// ------------------------------------------------- A and C row GEMMs (K=128)
// blocks 0..127: A rows 4b..4b+3 from X. blocks 128..255: C rows from eX=sums/cnt.
// Row operand is wave-uniform (s_load path); W1 row is per-lane float4, reused x4.
__global__ __launch_bounds__(256) void k_rows(
    const float* __restrict__ X, const float* __restrict__ W1,
    const float* __restrict__ b1, const float* __restrict__ sums,
    const float* __restrict__ cnt, float* __restrict__ A,
    float* __restrict__ C)
{
    int b = blockIdx.x;
    int h = threadIdx.x;          // 0..255
    int r0 = (b & 127) * 4;
    float acc0 = 0.f, acc1 = 0.f, acc2 = 0.f, acc3 = 0.f;

    if (b < 128) {
        const float* w  = W1 + h * (2 * DD);
        const float* x0 = X + (r0 + 0) * DD;
        const float* x1 = X + (r0 + 1) * DD;
        const float* x2 = X + (r0 + 2) * DD;
        const float* x3 = X + (r0 + 3) * DD;
        #pragma unroll 4
        for (int k = 0; k < DD; k += 4) {
            float4 wv = *(const float4*)(w + k);
            float4 v0 = *(const float4*)(x0 + k);
            float4 v1 = *(const float4*)(x1 + k);
            float4 v2 = *(const float4*)(x2 + k);
            float4 v3 = *(const float4*)(x3 + k);
            acc0 += wv.x * v0.x + wv.y * v0.y + wv.z * v0.z + wv.w * v0.w;
            acc1 += wv.x * v1.x + wv.y * v1.y + wv.z * v1.z + wv.w * v1.w;
            acc2 += wv.x * v2.x + wv.y * v2.y + wv.z * v2.z + wv.w * v2.w;
            acc3 += wv.x * v3.x + wv.y * v3.y + wv.z * v3.z + wv.w * v3.w;
        }
        A[(r0 + 0) * HH + h] = acc0;
        A[(r0 + 1) * HH + h] = acc1;
        A[(r0 + 2) * HH + h] = acc2;
        A[(r0 + 3) * HH + h] = acc3;
    } else {
        const float* w  = W1 + h * (2 * DD) + DD;
        float c0 = cnt[r0 + 0], c1 = cnt[r0 + 1], c2 = cnt[r0 + 2], c3 = cnt[r0 + 3];
        float i0 = c0 > 0.5f ? 1.0f / c0 : 0.0f;
        float i1 = c1 > 0.5f ? 1.0f / c1 : 0.0f;
        float i2 = c2 > 0.5f ? 1.0f / c2 : 0.0f;
        float i3 = c3 > 0.5f ? 1.0f / c3 : 0.0f;
        const float* s0 = sums + (r0 + 0) * DD;
        const float* s1 = sums + (r0 + 1) * DD;
        const float* s2 = sums + (r0 + 2) * DD;
        const float* s3 = sums + (r0 + 3) * DD;
        #pragma unroll 4
        for (int k = 0; k < DD; k += 4) {
            float4 wv = *(const float4*)(w + k);
            float4 v0 = *(const float4*)(s0 + k);
            float4 v1 = *(const float4*)(s1 + k);
            float4 v2 = *(const float4*)(s2 + k);
            float4 v3 = *(const float4*)(s3 + k);
            acc0 += wv.x * v0.x + wv.y * v0.y + wv.z * v0.z + wv.w * v0.w;
            acc1 += wv.x * v1.x + wv.y * v1.y + wv.z * v1.z + wv.w * v1.w;
            acc2 += wv.x * v2.x + wv.y * v2.y + wv.z * v2.z + wv.w * v2.w;
            acc3 += wv.x * v3.x + wv.y * v3.y + wv.z * v3.z + wv.w * v3.w;
        }
        float bb = b1[h];
        C[(r0 + 0) * HH + h] = acc0 * i0 + bb;
        C[(r0 + 1) * HH + h] = acc1 * i1 + bb;
        C[(r0 + 2) * HH + h] = acc2 * i2 + bb;
        C[(r0 + 3) * HH + h] = acc3 * i3 + bb;
    }
}

// --------------------------------------- logits + sigmoid: 32x32 tile / block
// LDS tiles in XOR-swizzled layout addr(r,h) = r*256 + (h ^ (r & 28)):
//  - staging writes (lanes vary h): banks = (tid ^ (r&28))%32 -> 2 lanes/bank, free
//  - compute reads b128 (h uniform, lanes vary r): 8 distinct 4-bank groups,
//    8-lane broadcast each -> conflict-free, no padding, exactly 64 KB.
// 4 waves split the h=256 dim (64 each), 4x4 accs per lane, LDS cross-wave reduce.
__global__ __launch_bounds__(256) void k_pairs(
    const float* __restrict__ A, const float* __restrict__ C,
    const float* __restrict__ W2, const float* __restrict__ b2,
    float* __restrict__ out)
{
    __shared__ float lds[16384];           // 64 KB: A-tile @0, C-tile @8192
    const int tid = threadIdx.x;
    const int bx = blockIdx.x;
    const int tn0 = (bx >> 4) * 32;
    const int tm0 = (bx & 15) * 32;

    #pragma unroll 4
    for (int r = 0; r < 32; ++r) {
        int sh = tid ^ (r & 28);
        lds[r * 256 + sh]        = A[(tn0 + r) * HH + tid];
        lds[8192 + r * 256 + sh] = C[(tm0 + r) * HH + tid];
    }
    __syncthreads();

    const int w    = tid >> 6;       // wave id = h-chunk
    const int lane = tid & 63;
    const int tr   = lane & 7;
    const int tc   = lane >> 3;
    const int ra   = 4 * tr;         // A-tile row base (multiple of 4 -> mask==ra)
    const int rc   = 4 * tc;         // C-tile row base
    const int h0   = w * 64;

    float acc[4][4];
    #pragma unroll
    for (int i = 0; i < 4; ++i)
        #pragma unroll
        for (int j = 0; j < 4; ++j) acc[i][j] = 0.f;

    const float* la = lds + ra * 256;
    const float* lc = lds + 8192 + rc * 256;

    #pragma unroll 2
    for (int hh = 0; hh < 64; hh += 4) {
        int h = h0 + hh;
        float4 wv = *(const float4*)(W2 + h);   // wave-uniform -> scalar load
        int sa = h ^ ra;                        // stays 4-aligned (masks bits 2-4)
        int sc = h ^ rc;
        float4 av[4], cv[4];
        #pragma unroll
        for (int i = 0; i < 4; ++i) av[i] = *(const float4*)(la + i * 256 + sa);
        #pragma unroll
        for (int j = 0; j < 4; ++j) cv[j] = *(const float4*)(lc + j * 256 + sc);
        #pragma unroll
        for (int i = 0; i < 4; ++i)
            #pragma unroll
            for (int j = 0; j < 4; ++j) {
                acc[i][j] += wv.x * fmaxf(av[i].x + cv[j].x, 0.f);
                acc[i][j] += wv.y * fmaxf(av[i].y + cv[j].y, 0.f);
                acc[i][j] += wv.z * fmaxf(av[i].z + cv[j].z, 0.f);
                acc[i][j] += wv.w * fmaxf(av[i].w + cv[j].w, 0.f);
            }
    }

    // cross-wave reduce through LDS (reuse tile space): red[k][w*64+lane]
    __syncthreads();
    #pragma unroll
    for (int i = 0; i < 4; ++i)
        #pragma unroll
        for (int j = 0; j < 4; ++j)
            lds[(i * 4 + j) * 256 + w * 64 + lane] = acc[i][j];
    __syncthreads();

    const float b2v = b2[0];
    const int lane0 = tid & 63;
    const int wq = tid >> 6;                  // which i (k>>2)
    float4 s;
    float* sp = &s.x;
    #pragma unroll
    for (int kk = 0; kk < 4; ++kk) {
        int k = wq * 4 + kk;
        float t = 0.f;
        #pragma unroll
        for (int ww = 0; ww < 4; ++ww) t += lds[k * 256 + ww * 64 + lane0];
        float logit = t + b2v;
        float p = 1.0f / (1.0f + __expf(-logit));
        p = fminf(fmaxf(p, 1e-6f), 1.0f - 1e-6f);
        sp[kk] = p;
    }
    int r = 4 * (lane0 & 7) + wq;
    int c = 4 * (lane0 >> 3);
    *(float4*)(out + (tn0 + r) * MM + tm0 + c) = s;
}

extern "C" void kernel_launch(void* const* d_in, const int* in_sizes, int n_in,
                              void* d_out, int out_size, void* d_ws, size_t ws_size,
                              hipStream_t stream)
{
    const float* X  = (const float*)d_in[0];
    const int*   V  = (const int*)d_in[1];
    const int*   E  = (const int*)d_in[2];
    const float* W1 = (const float*)d_in[3];
    const float* b1 = (const float*)d_in[4];
    const float* W2 = (const float*)d_in[5];
    const float* b2 = (const float*)d_in[6];

    float* ws   = (float*)d_ws;
    float* sums = ws + WS_SUMS;
    float* cnt  = ws + WS_CNT;
    float* A    = ws + WS_A;
    float* C    = ws + WS_C;
    float* out  = (float*)d_out;

    // zero the scatter accumulators (ws is poisoned 0xAA before every launch)
    hipMemsetAsync(d_ws, 0, (MM * DD + MM) * sizeof(float), stream);

    int ninc = in_sizes[1];                         // 8192
    k_scatter<<<(ninc * DD) / 256, 256, 0, stream>>>(X, V, E, sums, cnt);
    k_rows<<<256, 256, 0, stream>>>(X, W1, b1, sums, cnt, A, C);
    k_pairs<<<256, 256, 0, stream>>>(A, C, W2, b2, out);
}

// Round 2
// 93.830 us; speedup vs baseline: 1.0085x; 1.0085x over previous
//
#include <hip/hip_runtime.h>
#include <math.h>

#define NN 512   // nodes
#define MM 512   // edges
#define DD 128   // emb dim
#define HH 256   // hidden

// ws layout (float offsets)
#define WS_A 0               // A[n][h] = X[n,:].W1[h,0:128]
#define WS_C (NN * HH)       // C[m][h] = eX[m,:].W1[h,128:256] + b1[h]

// ---------------------------------------------------------------------------
// Kernel 1: blocks 0..511  -> per-edge gather-mean + C row (no global atomics)
//           blocks 512..639 -> A rows (4 node rows per block)
// ---------------------------------------------------------------------------
__global__ __launch_bounds__(256) void k_stage(
    const float* __restrict__ X, const int* __restrict__ V,
    const int* __restrict__ E, const float* __restrict__ W1,
    const float* __restrict__ b1, float* __restrict__ A,
    float* __restrict__ C, int ninc)
{
    __shared__ int   lst[8192];     // worst-case all incidences on one edge
    __shared__ float eXp[2 * DD];
    __shared__ float eXs[DD];
    __shared__ int   cnt_s;

    const int b = blockIdx.x;
    const int t = threadIdx.x;

    if (b < MM) {
        // ---- phase A: scan incidence->edge array, collect matches ----
        if (t == 0) cnt_s = 0;
        __syncthreads();
        for (int i = t; i < ninc; i += 256)
            if (E[i] == b) lst[atomicAdd(&cnt_s, 1)] = i;
        __syncthreads();
        const int cnt = cnt_s;

        // ---- phase B: gather-sum X rows (2 halves x 2-deep unroll) ----
        const int d = t & 127, half = t >> 7;
        float a0 = 0.f, a1 = 0.f;
        int j = half;
        for (; j + 2 < cnt; j += 4) {
            int i0 = lst[j], i1 = lst[j + 2];
            a0 += X[V[i0] * DD + d];
            a1 += X[V[i1] * DD + d];
        }
        for (; j < cnt; j += 2) a0 += X[V[lst[j]] * DD + d];
        eXp[half * DD + d] = a0 + a1;
        __syncthreads();
        if (t < DD) {
            float inv = cnt > 0 ? 1.0f / (float)cnt : 0.0f;
            eXs[t] = (eXp[t] + eXp[DD + t]) * inv;
        }
        __syncthreads();

        // ---- phase C: C[b][h] = b1[h] + eX . W1[h,128:256] ----
        const float* w = W1 + t * (2 * DD) + DD;
        float dot = b1[t];
        #pragma unroll 8
        for (int k = 0; k < DD; k += 4) {
            float4 wv = *(const float4*)(w + k);
            float4 ev = *(const float4*)(&eXs[k]);
            dot += wv.x * ev.x + wv.y * ev.y + wv.z * ev.z + wv.w * ev.w;
        }
        C[b * HH + t] = dot;
    } else {
        // ---- A rows: 4 node rows per block, row operand wave-uniform ----
        const int r0 = (b - MM) * 4;
        const float* w  = W1 + t * (2 * DD);
        const float* x0 = X + (r0 + 0) * DD;
        const float* x1 = X + (r0 + 1) * DD;
        const float* x2 = X + (r0 + 2) * DD;
        const float* x3 = X + (r0 + 3) * DD;
        float acc0 = 0.f, acc1 = 0.f, acc2 = 0.f, acc3 = 0.f;
        #pragma unroll 4
        for (int k = 0; k < DD; k += 4) {
            float4 wv = *(const float4*)(w + k);
            float4 v0 = *(const float4*)(x0 + k);
            float4 v1 = *(const float4*)(x1 + k);
            float4 v2 = *(const float4*)(x2 + k);
            float4 v3 = *(const float4*)(x3 + k);
            acc0 += wv.x * v0.x + wv.y * v0.y + wv.z * v0.z + wv.w * v0.w;
            acc1 += wv.x * v1.x + wv.y * v1.y + wv.z * v1.z + wv.w * v1.w;
            acc2 += wv.x * v2.x + wv.y * v2.y + wv.z * v2.z + wv.w * v2.w;
            acc3 += wv.x * v3.x + wv.y * v3.y + wv.z * v3.z + wv.w * v3.w;
        }
        A[(r0 + 0) * HH + t] = acc0;
        A[(r0 + 1) * HH + t] = acc1;
        A[(r0 + 2) * HH + t] = acc2;
        A[(r0 + 3) * HH + t] = acc3;
    }
}

// ---------------------------------------------------------------------------
// Kernel 2: logits+sigmoid, 16x16 tile / block, 1024 blocks (4/CU, 4 waves/SIMD)
// LDS XOR swizzle addr(r,h)=r*256+(h^(r&28)): staging writes consecutive-bank,
// compute b128 reads 2-way-per-bank (free on gfx950) + 8-lane broadcast.
// 4 waves split h=256 (64 each), 2x2 accs/lane, LDS cross-wave reduce.
// ---------------------------------------------------------------------------
__global__ __launch_bounds__(256) void k_pairs(
    const float* __restrict__ A, const float* __restrict__ C,
    const float* __restrict__ W2, const float* __restrict__ b2,
    float* __restrict__ out)
{
    __shared__ float lds[8192];          // A-tile [0,4096), C-tile [4096,8192)
    const int tid = threadIdx.x;
    const int bx  = blockIdx.x;
    const int tn0 = (bx >> 5) * 16;
    const int tm0 = (bx & 31) * 16;

    // staging: each wave loads one full row (256 floats) per tile per pass
    {
        const int c0 = (tid & 63) * 4;
        const int rw = tid >> 6;
        #pragma unroll
        for (int p = 0; p < 4; ++p) {
            int r  = p * 4 + rw;
            int sh = c0 ^ (r & 28);
            *(float4*)&lds[r * 256 + sh]        = *(const float4*)&A[(tn0 + r) * HH + c0];
            *(float4*)&lds[4096 + r * 256 + sh] = *(const float4*)&C[(tm0 + r) * HH + c0];
        }
    }
    __syncthreads();

    const int w = tid >> 6, lane = tid & 63;
    const int ra = 2 * (lane & 7);       // A rows {ra, ra+1}
    const int rc = 2 * (lane >> 3);      // C rows {rc, rc+1}
    const int pa = ra & 28, pc = rc & 28;
    const int h0 = w * 64;

    float a00 = 0.f, a01 = 0.f, a10 = 0.f, a11 = 0.f;
    const float* la = lds + ra * 256;
    const float* lc = lds + 4096 + rc * 256;

    #pragma unroll 4
    for (int hh = 0; hh < 64; hh += 4) {
        int h = h0 + hh;
        float4 wv  = *(const float4*)(W2 + h);          // wave-uniform
        float4 av0 = *(const float4*)(la + (h ^ pa));
        float4 av1 = *(const float4*)(la + 256 + (h ^ pa));
        float4 cv0 = *(const float4*)(lc + (h ^ pc));
        float4 cv1 = *(const float4*)(lc + 256 + (h ^ pc));
        a00 += wv.x * fmaxf(av0.x + cv0.x, 0.f) + wv.y * fmaxf(av0.y + cv0.y, 0.f)
             + wv.z * fmaxf(av0.z + cv0.z, 0.f) + wv.w * fmaxf(av0.w + cv0.w, 0.f);
        a01 += wv.x * fmaxf(av0.x + cv1.x, 0.f) + wv.y * fmaxf(av0.y + cv1.y, 0.f)
             + wv.z * fmaxf(av0.z + cv1.z, 0.f) + wv.w * fmaxf(av0.w + cv1.w, 0.f);
        a10 += wv.x * fmaxf(av1.x + cv0.x, 0.f) + wv.y * fmaxf(av1.y + cv0.y, 0.f)
             + wv.z * fmaxf(av1.z + cv0.z, 0.f) + wv.w * fmaxf(av1.w + cv0.w, 0.f);
        a11 += wv.x * fmaxf(av1.x + cv1.x, 0.f) + wv.y * fmaxf(av1.y + cv1.y, 0.f)
             + wv.z * fmaxf(av1.z + cv1.z, 0.f) + wv.w * fmaxf(av1.w + cv1.w, 0.f);
    }

    // cross-wave reduce through LDS (reuse tile space): red[w][p], p=r*16+c
    __syncthreads();
    lds[w * 256 + (ra + 0) * 16 + (rc + 0)] = a00;
    lds[w * 256 + (ra + 0) * 16 + (rc + 1)] = a01;
    lds[w * 256 + (ra + 1) * 16 + (rc + 0)] = a10;
    lds[w * 256 + (ra + 1) * 16 + (rc + 1)] = a11;
    __syncthreads();

    const int p = tid;                   // 0..255 -> (r,c) in tile
    float s = lds[p] + lds[256 + p] + lds[512 + p] + lds[768 + p] + b2[0];
    float prob = 1.0f / (1.0f + __expf(-s));
    prob = fminf(fmaxf(prob, 1e-6f), 1.0f - 1e-6f);
    out[(tn0 + (p >> 4)) * MM + tm0 + (p & 15)] = prob;
}

extern "C" void kernel_launch(void* const* d_in, const int* in_sizes, int n_in,
                              void* d_out, int out_size, void* d_ws, size_t ws_size,
                              hipStream_t stream)
{
    const float* X  = (const float*)d_in[0];
    const int*   V  = (const int*)d_in[1];
    const int*   E  = (const int*)d_in[2];
    const float* W1 = (const float*)d_in[3];
    const float* b1 = (const float*)d_in[4];
    const float* W2 = (const float*)d_in[5];
    const float* b2 = (const float*)d_in[6];

    float* ws  = (float*)d_ws;
    float* A   = ws + WS_A;
    float* C   = ws + WS_C;
    float* out = (float*)d_out;

    int ninc = in_sizes[1];   // 8192

    k_stage<<<MM + NN / 4, 256, 0, stream>>>(X, V, E, W1, b1, A, C, ninc);
    k_pairs<<<(NN / 16) * (MM / 16), 256, 0, stream>>>(A, C, W2, b2, out);
}

// Round 4
// 88.489 us; speedup vs baseline: 1.0694x; 1.0604x over previous
//
#include <hip/hip_runtime.h>
#include <math.h>

#define NN 512   // nodes
#define MM 512   // edges
#define DD 128   // emb dim
#define HH 256   // hidden

typedef float v4f __attribute__((ext_vector_type(4)));

// ws layout (float offsets)
#define WS_A 0               // A[n][h] = X[n,:].W1[h,0:128]
#define WS_C (NN * HH)       // C[m][h] = eX[m,:].W1[h,128:256] + b1[h]

// ---------------------------------------------------------------------------
// Kernel 1: blocks 0..511   -> per-edge gather-mean + C row (no global atomics)
//           blocks 512..639 -> A rows, 4 node rows per block (W1 reuse x4)
// ---------------------------------------------------------------------------
__global__ __launch_bounds__(256) void k_stage(
    const float* __restrict__ X, const int* __restrict__ V,
    const int* __restrict__ E, const float* __restrict__ W1,
    const float* __restrict__ b1, float* __restrict__ A,
    float* __restrict__ C, int ninc)
{
    __shared__ int   lst[8192];
    __shared__ float eXp[2 * DD];
    __shared__ float eXs[DD];
    __shared__ int   cnt_s;

    const int b = blockIdx.x;
    const int t = threadIdx.x;

    if (b < MM) {
        // ---- phase A: vectorized scan of E, collect matching incidences ----
        if (t == 0) cnt_s = 0;
        __syncthreads();
        const int nq = ninc >> 2;
        for (int c = t; c < nq; c += 256) {
            int4 e4 = ((const int4*)E)[c];
            int base = c * 4;
            if (e4.x == b) lst[atomicAdd(&cnt_s, 1)] = base + 0;
            if (e4.y == b) lst[atomicAdd(&cnt_s, 1)] = base + 1;
            if (e4.z == b) lst[atomicAdd(&cnt_s, 1)] = base + 2;
            if (e4.w == b) lst[atomicAdd(&cnt_s, 1)] = base + 3;
        }
        __syncthreads();
        const int cnt = cnt_s;

        // ---- phase B: gather-sum X rows (2 halves x 2-deep unroll) ----
        const int d = t & 127, half = t >> 7;
        float a0 = 0.f, a1 = 0.f;
        int j = half;
        for (; j + 2 < cnt; j += 4) {
            int i0 = lst[j], i1 = lst[j + 2];
            a0 += X[V[i0] * DD + d];
            a1 += X[V[i1] * DD + d];
        }
        for (; j < cnt; j += 2) a0 += X[V[lst[j]] * DD + d];
        eXp[half * DD + d] = a0 + a1;
        __syncthreads();
        if (t < DD) {
            float inv = cnt > 0 ? 1.0f / (float)cnt : 0.0f;
            eXs[t] = (eXp[t] + eXp[DD + t]) * inv;
        }
        __syncthreads();

        // ---- phase C: C[b][h] = b1[h] + eX . W1[h,128:256] ----
        const float* w = W1 + t * (2 * DD) + DD;
        v4f dv = (v4f)(0.f);
        #pragma unroll 8
        for (int k = 0; k < DD; k += 4)
            dv += (*(const v4f*)(w + k)) * (*(const v4f*)(eXs + k));
        C[b * HH + t] = b1[t] + dv.x + dv.y + dv.z + dv.w;
    } else {
        // ---- A rows: 4 node rows per block, row operands wave-uniform ----
        const int r0 = (b - MM) * 4;
        const float* w  = W1 + t * (2 * DD);
        const float* x0 = X + (r0 + 0) * DD;
        const float* x1 = X + (r0 + 1) * DD;
        const float* x2 = X + (r0 + 2) * DD;
        const float* x3 = X + (r0 + 3) * DD;
        v4f acc0 = (v4f)(0.f), acc1 = (v4f)(0.f), acc2 = (v4f)(0.f), acc3 = (v4f)(0.f);
        #pragma unroll 4
        for (int k = 0; k < DD; k += 4) {
            v4f wv = *(const v4f*)(w + k);
            acc0 += wv * (*(const v4f*)(x0 + k));
            acc1 += wv * (*(const v4f*)(x1 + k));
            acc2 += wv * (*(const v4f*)(x2 + k));
            acc3 += wv * (*(const v4f*)(x3 + k));
        }
        A[(r0 + 0) * HH + t] = acc0.x + acc0.y + acc0.z + acc0.w;
        A[(r0 + 1) * HH + t] = acc1.x + acc1.y + acc1.z + acc1.w;
        A[(r0 + 2) * HH + t] = acc2.x + acc2.y + acc2.z + acc2.w;
        A[(r0 + 3) * HH + t] = acc3.x + acc3.y + acc3.z + acc3.w;
    }
}

// ---------------------------------------------------------------------------
// Kernel 2: logits+sigmoid, 16x16 tile / block, 1024 blocks (4/CU).
// LDS XOR swizzle addr(r,h)=r*256+(h^(r&28)): conflict-free b128 reads.
// Inner math in <4 x float> vector ops to allow v_pk_* packed fp32 selection.
// ---------------------------------------------------------------------------
__global__ __launch_bounds__(256) void k_pairs(
    const float* __restrict__ A, const float* __restrict__ C,
    const float* __restrict__ W2, const float* __restrict__ b2,
    float* __restrict__ out)
{
    __shared__ float lds[8192];          // A-tile [0,4096), C-tile [4096,8192)
    const int tid = threadIdx.x;
    const int bx  = blockIdx.x;
    const int tn0 = (bx >> 5) * 16;
    const int tm0 = (bx & 31) * 16;

    {
        const int c0 = (tid & 63) * 4;
        const int rw = tid >> 6;
        #pragma unroll
        for (int p = 0; p < 4; ++p) {
            int r  = p * 4 + rw;
            int sh = c0 ^ (r & 28);
            *(float4*)&lds[r * 256 + sh]        = *(const float4*)&A[(tn0 + r) * HH + c0];
            *(float4*)&lds[4096 + r * 256 + sh] = *(const float4*)&C[(tm0 + r) * HH + c0];
        }
    }
    __syncthreads();

    const int w = tid >> 6, lane = tid & 63;
    const int ra = 2 * (lane & 7);       // A rows {ra, ra+1}
    const int rc = 2 * (lane >> 3);      // C rows {rc, rc+1}
    const int pa = ra & 28, pc = rc & 28;
    const int h0 = w * 64;

    v4f s00 = (v4f)(0.f), s01 = (v4f)(0.f), s10 = (v4f)(0.f), s11 = (v4f)(0.f);
    const v4f z = (v4f)(0.f);
    const float* la = lds + ra * 256;
    const float* lc = lds + 4096 + rc * 256;

    #pragma unroll 4
    for (int hh = 0; hh < 64; hh += 4) {
        int h = h0 + hh;
        v4f wv  = *(const v4f*)(W2 + h);          // wave-uniform -> s_load
        v4f av0 = *(const v4f*)(la + (h ^ pa));
        v4f av1 = *(const v4f*)(la + 256 + (h ^ pa));
        v4f cv0 = *(const v4f*)(lc + (h ^ pc));
        v4f cv1 = *(const v4f*)(lc + 256 + (h ^ pc));
        s00 += wv * __builtin_elementwise_max(av0 + cv0, z);
        s01 += wv * __builtin_elementwise_max(av0 + cv1, z);
        s10 += wv * __builtin_elementwise_max(av1 + cv0, z);
        s11 += wv * __builtin_elementwise_max(av1 + cv1, z);
    }
    float a00 = s00.x + s00.y + s00.z + s00.w;
    float a01 = s01.x + s01.y + s01.z + s01.w;
    float a10 = s10.x + s10.y + s10.z + s10.w;
    float a11 = s11.x + s11.y + s11.z + s11.w;

    // cross-wave reduce through LDS (reuse tile space): red[w][p], p=r*16+c
    __syncthreads();
    lds[w * 256 + (ra + 0) * 16 + (rc + 0)] = a00;
    lds[w * 256 + (ra + 0) * 16 + (rc + 1)] = a01;
    lds[w * 256 + (ra + 1) * 16 + (rc + 0)] = a10;
    lds[w * 256 + (ra + 1) * 16 + (rc + 1)] = a11;
    __syncthreads();

    const int p = tid;                   // 0..255 -> (r,c) in tile
    float s = lds[p] + lds[256 + p] + lds[512 + p] + lds[768 + p] + b2[0];
    float prob = 1.0f / (1.0f + __expf(-s));
    prob = fminf(fmaxf(prob, 1e-6f), 1.0f - 1e-6f);
    out[(tn0 + (p >> 4)) * MM + tm0 + (p & 15)] = prob;
}

extern "C" void kernel_launch(void* const* d_in, const int* in_sizes, int n_in,
                              void* d_out, int out_size, void* d_ws, size_t ws_size,
                              hipStream_t stream)
{
    const float* X  = (const float*)d_in[0];
    const int*   V  = (const int*)d_in[1];
    const int*   E  = (const int*)d_in[2];
    const float* W1 = (const float*)d_in[3];
    const float* b1 = (const float*)d_in[4];
    const float* W2 = (const float*)d_in[5];
    const float* b2 = (const float*)d_in[6];

    float* ws  = (float*)d_ws;
    float* A   = ws + WS_A;
    float* C   = ws + WS_C;
    float* out = (float*)d_out;
    int ninc   = in_sizes[1];   // 8192

    k_stage<<<MM + NN / 4, 256, 0, stream>>>(X, V, E, W1, b1, A, C, ninc);
    k_pairs<<<(NN / 16) * (MM / 16), 256, 0, stream>>>(A, C, W2, b2, out);
}

// Round 5
// 85.112 us; speedup vs baseline: 1.1118x; 1.0397x over previous
//
#include <hip/hip_runtime.h>
#include <math.h>

#define NN 512   // nodes
#define MM 512   // edges
#define DD 128   // emb dim
#define HH 256   // hidden

typedef float     v4f __attribute__((ext_vector_type(4)));
typedef _Float16  h8  __attribute__((ext_vector_type(8)));
typedef _Float16  h2  __attribute__((ext_vector_type(2)));

// ws layout: A, C stored as fp16 (halves global+LDS traffic of the pair phase)
// A[n][h] = X[n,:].W1[h,0:128];  C[m][h] = b1[h] + eX[m,:].W1[h,128:256]

// ---------------------------------------------------------------------------
// Kernel 1: blocks 0..511   -> per-edge gather-mean + C row (no global atomics)
//           blocks 512..639 -> A rows, 4 node rows per block (W1 reuse x4)
// ---------------------------------------------------------------------------
__global__ __launch_bounds__(256) void k_stage(
    const float* __restrict__ X, const int* __restrict__ V,
    const int* __restrict__ E, const float* __restrict__ W1,
    const float* __restrict__ b1, _Float16* __restrict__ A,
    _Float16* __restrict__ C, int ninc)
{
    __shared__ int   lst[8192];     // V-indices of matching incidences
    __shared__ float eXp[2 * DD];
    __shared__ float eXs[DD];
    __shared__ int   cnt_s;

    const int b = blockIdx.x;
    const int t = threadIdx.x;

    if (b < MM) {
        // ---- phase A: vectorized scan of E; store V[i] directly (cuts one
        //      dependent-load level from the gather chain) ----
        if (t == 0) cnt_s = 0;
        __syncthreads();
        const int nq = ninc >> 2;
        for (int c = t; c < nq; c += 256) {
            int4 e4 = ((const int4*)E)[c];
            int base = c * 4;
            if (e4.x == b) lst[atomicAdd(&cnt_s, 1)] = V[base + 0];
            if (e4.y == b) lst[atomicAdd(&cnt_s, 1)] = V[base + 1];
            if (e4.z == b) lst[atomicAdd(&cnt_s, 1)] = V[base + 2];
            if (e4.w == b) lst[atomicAdd(&cnt_s, 1)] = V[base + 3];
        }
        __syncthreads();
        const int cnt = cnt_s;

        // ---- phase B: gather-sum X rows (2 halves x 2-deep unroll) ----
        const int d = t & 127, half = t >> 7;
        float a0 = 0.f, a1 = 0.f;
        int j = half;
        for (; j + 2 < cnt; j += 4) {
            int v0 = lst[j], v1 = lst[j + 2];
            a0 += X[v0 * DD + d];
            a1 += X[v1 * DD + d];
        }
        for (; j < cnt; j += 2) a0 += X[lst[j] * DD + d];
        eXp[half * DD + d] = a0 + a1;
        __syncthreads();
        if (t < DD) {
            float inv = cnt > 0 ? 1.0f / (float)cnt : 0.0f;
            eXs[t] = (eXp[t] + eXp[DD + t]) * inv;
        }
        __syncthreads();

        // ---- phase C: C[b][h] = b1[h] + eX . W1[h,128:256] ----
        const float* w = W1 + t * (2 * DD) + DD;
        v4f dv = (v4f)(0.f);
        #pragma unroll 8
        for (int k = 0; k < DD; k += 4)
            dv += (*(const v4f*)(w + k)) * (*(const v4f*)(eXs + k));
        C[b * HH + t] = (_Float16)(b1[t] + dv.x + dv.y + dv.z + dv.w);
    } else {
        // ---- A rows: 4 node rows per block, row operands wave-uniform ----
        const int r0 = (b - MM) * 4;
        const float* w  = W1 + t * (2 * DD);
        const float* x0 = X + (r0 + 0) * DD;
        const float* x1 = X + (r0 + 1) * DD;
        const float* x2 = X + (r0 + 2) * DD;
        const float* x3 = X + (r0 + 3) * DD;
        v4f acc0 = (v4f)(0.f), acc1 = (v4f)(0.f), acc2 = (v4f)(0.f), acc3 = (v4f)(0.f);
        #pragma unroll 4
        for (int k = 0; k < DD; k += 4) {
            v4f wv = *(const v4f*)(w + k);
            acc0 += wv * (*(const v4f*)(x0 + k));
            acc1 += wv * (*(const v4f*)(x1 + k));
            acc2 += wv * (*(const v4f*)(x2 + k));
            acc3 += wv * (*(const v4f*)(x3 + k));
        }
        A[(r0 + 0) * HH + t] = (_Float16)(acc0.x + acc0.y + acc0.z + acc0.w);
        A[(r0 + 1) * HH + t] = (_Float16)(acc1.x + acc1.y + acc1.z + acc1.w);
        A[(r0 + 2) * HH + t] = (_Float16)(acc2.x + acc2.y + acc2.z + acc2.w);
        A[(r0 + 3) * HH + t] = (_Float16)(acc3.x + acc3.y + acc3.z + acc3.w);
    }
}

// ---------------------------------------------------------------------------
// Kernel 2: logits+sigmoid, 16x16 tile / block, 1024 blocks (4/CU).
// fp16 LDS tiles, padded rows (264 halves = 528 B -> row bank-group = r%8,
// 2-way aliasing on compute reads = free per m136). relu(a+c) in packed fp16,
// fp32 accumulate via v_dot2_f32_f16 — halves LDS traffic vs fp32 tiles.
// ---------------------------------------------------------------------------
#define ROWH 264                       // halves per padded LDS row
#define CT   (16 * ROWH)               // C-tile offset (half idx) = 4224
#define WT   (32 * ROWH)               // w2 offset (half idx)     = 8448

__device__ inline float dot8(h8 w, h8 a, h8 c, float acc) {
    h8 s = a + c;
    s = __builtin_elementwise_max(s, (h8)(_Float16)0.f);
    union { h8 v; h2 p[4]; } su, wu;
    su.v = s; wu.v = w;
    acc = __builtin_amdgcn_fdot2(su.p[0], wu.p[0], acc, false);
    acc = __builtin_amdgcn_fdot2(su.p[1], wu.p[1], acc, false);
    acc = __builtin_amdgcn_fdot2(su.p[2], wu.p[2], acc, false);
    acc = __builtin_amdgcn_fdot2(su.p[3], wu.p[3], acc, false);
    return acc;
}

__global__ __launch_bounds__(256) void k_pairs(
    const _Float16* __restrict__ A, const _Float16* __restrict__ C,
    const float* __restrict__ W2, const float* __restrict__ b2,
    float* __restrict__ out)
{
    __shared__ _Float16 lds[WT + 256];     // 17.4 KB: A-tile, C-tile, w2(fp16)
    const int t  = threadIdx.x;
    const int bx = blockIdx.x;
    const int tn0 = (bx >> 5) * 16;
    const int tm0 = (bx & 31) * 16;

    // stage: w2 -> fp16; A/C tiles as 16-B chunks (8 halves), coalesced
    lds[WT + t] = (_Float16)W2[t];
    #pragma unroll
    for (int p = 0; p < 4; ++p) {
        int g = p * 256 + t;               // 0..1023 chunk id
        int row = g >> 5, c8 = (g & 31) * 8;
        const _Float16* src;
        int dst;
        if (row < 16) { src = A + (tn0 + row) * HH + c8;        dst = row * ROWH + c8; }
        else          { src = C + (tm0 + row - 16) * HH + c8;   dst = CT + (row - 16) * ROWH + c8; }
        *(h8*)&lds[dst] = *(const h8*)src;
    }
    __syncthreads();

    const int w = t >> 6, lane = t & 63;
    const int ra = 2 * (lane & 7);         // A rows {ra, ra+1}
    const int rc = 2 * (lane >> 3);        // C rows {rc, rc+1}
    const _Float16* la = lds + ra * ROWH + w * 64;
    const _Float16* lc = lds + CT + rc * ROWH + w * 64;
    const _Float16* lw = lds + WT + w * 64;

    float a00 = 0.f, a01 = 0.f, a10 = 0.f, a11 = 0.f;
    #pragma unroll
    for (int hh = 0; hh < 64; hh += 8) {
        h8 wv  = *(const h8*)(lw + hh);            // wave-uniform -> broadcast
        h8 av0 = *(const h8*)(la + hh);
        h8 av1 = *(const h8*)(la + ROWH + hh);
        h8 cv0 = *(const h8*)(lc + hh);
        h8 cv1 = *(const h8*)(lc + ROWH + hh);
        a00 = dot8(wv, av0, cv0, a00);
        a01 = dot8(wv, av0, cv1, a01);
        a10 = dot8(wv, av1, cv0, a10);
        a11 = dot8(wv, av1, cv1, a11);
    }

    // cross-wave reduce through LDS (reuse tile space as fp32): red[w][p]
    __syncthreads();
    float* red = (float*)lds;
    red[w * 256 + (ra + 0) * 16 + (rc + 0)] = a00;
    red[w * 256 + (ra + 0) * 16 + (rc + 1)] = a01;
    red[w * 256 + (ra + 1) * 16 + (rc + 0)] = a10;
    red[w * 256 + (ra + 1) * 16 + (rc + 1)] = a11;
    __syncthreads();

    const int p = t;                       // 0..255 -> (r,c) in tile
    float s = red[p] + red[256 + p] + red[512 + p] + red[768 + p] + b2[0];
    float prob = 1.0f / (1.0f + __expf(-s));
    prob = fminf(fmaxf(prob, 1e-6f), 1.0f - 1e-6f);
    out[(tn0 + (p >> 4)) * MM + tm0 + (p & 15)] = prob;
}

extern "C" void kernel_launch(void* const* d_in, const int* in_sizes, int n_in,
                              void* d_out, int out_size, void* d_ws, size_t ws_size,
                              hipStream_t stream)
{
    const float* X  = (const float*)d_in[0];
    const int*   V  = (const int*)d_in[1];
    const int*   E  = (const int*)d_in[2];
    const float* W1 = (const float*)d_in[3];
    const float* b1 = (const float*)d_in[4];
    const float* W2 = (const float*)d_in[5];
    const float* b2 = (const float*)d_in[6];

    _Float16* A = (_Float16*)d_ws;
    _Float16* C = A + NN * HH;
    float* out  = (float*)d_out;
    int ninc    = in_sizes[1];   // 8192

    k_stage<<<MM + NN / 4, 256, 0, stream>>>(X, V, E, W1, b1, A, C, ninc);
    k_pairs<<<(NN / 16) * (MM / 16), 256, 0, stream>>>(A, C, W2, b2, out);
}

// Round 6
// 84.662 us; speedup vs baseline: 1.1177x; 1.0053x over previous
//
#include <hip/hip_runtime.h>
#include <math.h>

#define NN 512   // nodes
#define MM 512   // edges
#define DD 128   // emb dim
#define HH 256   // hidden

typedef float     v4f __attribute__((ext_vector_type(4)));
typedef _Float16  h8  __attribute__((ext_vector_type(8)));
typedef _Float16  h2  __attribute__((ext_vector_type(2)));

// ws: A[n][h] (fp16), C[m][h] (fp16). A = X.W1a^T, C = b1 + eX.W1b^T.

// ---------------------------------------------------------------------------
// k_stage: 256 blocks. b<128 -> edge-quad (4 edges: scan+gather-mean+GEMV),
//          b>=128 -> node-quad (4 X rows: GEMV). Unified W1-tiled GEMV:
//   - W1 tile 64h x 128k staged to LDS with coalesced global loads,
//     XOR-swizzled float4 slots (kq ^ (h&31)) -> conflict-free write+read
//   - 4 waves k-split (8 chunks each), LDS cross-wave reduce
// ---------------------------------------------------------------------------
__global__ __launch_bounds__(256) void k_stage(
    const float* __restrict__ X, const int* __restrict__ V,
    const int* __restrict__ E, const float* __restrict__ W1,
    const float* __restrict__ b1, _Float16* __restrict__ A,
    _Float16* __restrict__ C, int ninc)
{
    __shared__ union {
        int    lst[8192];          // edge phase: V-indices grouped by edge
        float4 w1t[64][32];        // GEMV phase: W1 tile (swizzled)
    } u;
    __shared__ float xr[4][128];   // 4 source rows (X rows or eX means)
    __shared__ float red[16][64];  // cross-wave partials [w*4+r][h]
    __shared__ int   cnt4[4], pos4[4], off4[4];

    const int b = blockIdx.x;
    const int t = threadIdx.x;
    const int w = t >> 6, lane = t & 63;
    const bool edge = (b < 128);

    if (edge) {
        const int e0 = b * 4;
        if (t < 4) { cnt4[t] = 0; pos4[t] = 0; }
        __syncthreads();
        const int nq = ninc >> 2;
        // pass 1: count incidences per edge
        for (int c = t; c < nq; c += 256) {
            int4 e4 = ((const int4*)E)[c];
            if ((unsigned)(e4.x - e0) < 4u) atomicAdd(&cnt4[e4.x - e0], 1);
            if ((unsigned)(e4.y - e0) < 4u) atomicAdd(&cnt4[e4.y - e0], 1);
            if ((unsigned)(e4.z - e0) < 4u) atomicAdd(&cnt4[e4.z - e0], 1);
            if ((unsigned)(e4.w - e0) < 4u) atomicAdd(&cnt4[e4.w - e0], 1);
        }
        __syncthreads();
        if (t == 0) {
            off4[0] = 0;
            off4[1] = cnt4[0];
            off4[2] = cnt4[0] + cnt4[1];
            off4[3] = off4[2] + cnt4[2];
        }
        __syncthreads();
        // pass 2: place V-indices grouped by edge
        for (int c = t; c < nq; c += 256) {
            int4 e4 = ((const int4*)E)[c];
            int4 v4 = ((const int4*)V)[c];
            if ((unsigned)(e4.x - e0) < 4u) u.lst[off4[e4.x-e0] + atomicAdd(&pos4[e4.x-e0], 1)] = v4.x;
            if ((unsigned)(e4.y - e0) < 4u) u.lst[off4[e4.y-e0] + atomicAdd(&pos4[e4.y-e0], 1)] = v4.y;
            if ((unsigned)(e4.z - e0) < 4u) u.lst[off4[e4.z-e0] + atomicAdd(&pos4[e4.z-e0], 1)] = v4.z;
            if ((unsigned)(e4.w - e0) < 4u) u.lst[off4[e4.w-e0] + atomicAdd(&pos4[e4.w-e0], 1)] = v4.w;
        }
        __syncthreads();
        // gather-mean: wave w -> edge e0+w; lane covers dims {lane, lane+64};
        // 4-deep unroll keeps 8 global loads in flight per lane.
        const int cnt = cnt4[w], off = off4[w];
        float s0a=0.f,s0b=0.f,s0c=0.f,s0d=0.f, s1a=0.f,s1b=0.f,s1c=0.f,s1d=0.f;
        int j = 0;
        for (; j + 4 <= cnt; j += 4) {
            int v0 = u.lst[off+j], v1 = u.lst[off+j+1], v2 = u.lst[off+j+2], v3 = u.lst[off+j+3];
            s0a += X[v0*DD + lane];      s1a += X[v0*DD + 64 + lane];
            s0b += X[v1*DD + lane];      s1b += X[v1*DD + 64 + lane];
            s0c += X[v2*DD + lane];      s1c += X[v2*DD + 64 + lane];
            s0d += X[v3*DD + lane];      s1d += X[v3*DD + 64 + lane];
        }
        for (; j < cnt; ++j) {
            int v = u.lst[off+j];
            s0a += X[v*DD + lane];       s1a += X[v*DD + 64 + lane];
        }
        float inv = cnt > 0 ? 1.0f / (float)cnt : 0.0f;
        xr[w][lane]      = (s0a+s0b+s0c+s0d) * inv;
        xr[w][lane+64]   = (s1a+s1b+s1c+s1d) * inv;
        __syncthreads();                 // xr ready; lst reads done (union safe)
    } else {
        const int r0 = (b - 128) * 4;
        ((float*)xr)[t]       = X[r0*DD + t];
        ((float*)xr)[t + 256] = X[r0*DD + 256 + t];
        __syncthreads();
    }

    const int r0row = edge ? b*4 : (b-128)*4;
    const int koff  = edge ? DD : 0;
    _Float16* Out   = edge ? C : A;

    #pragma unroll 1
    for (int p = 0; p < 4; ++p) {
        const int h0 = p * 64;
        // stage W1 tile (64 h x 32 float4-chunks), coalesced global reads
        #pragma unroll
        for (int q = 0; q < 8; ++q) {
            int c  = q * 256 + t;
            int h  = c >> 5, kq = c & 31;
            u.w1t[h][kq ^ (h & 31)] =
                *(const float4*)&W1[(h0 + h) * (2*DD) + koff + kq * 4];
        }
        __syncthreads();
        // compute: wave w -> k-quarter (8 chunks), lane -> h
        v4f acc0 = (v4f)(0.f), acc1 = (v4f)(0.f), acc2 = (v4f)(0.f), acc3 = (v4f)(0.f);
        #pragma unroll
        for (int i = 0; i < 8; ++i) {
            int kq = w * 8 + i;
            v4f wv = *(const v4f*)&u.w1t[lane][kq ^ (lane & 31)];
            acc0 += wv * (*(const v4f*)&xr[0][kq*4]);   // xr: wave-uniform -> broadcast
            acc1 += wv * (*(const v4f*)&xr[1][kq*4]);
            acc2 += wv * (*(const v4f*)&xr[2][kq*4]);
            acc3 += wv * (*(const v4f*)&xr[3][kq*4]);
        }
        red[w*4 + 0][lane] = acc0.x + acc0.y + acc0.z + acc0.w;
        red[w*4 + 1][lane] = acc1.x + acc1.y + acc1.z + acc1.w;
        red[w*4 + 2][lane] = acc2.x + acc2.y + acc2.z + acc2.w;
        red[w*4 + 3][lane] = acc3.x + acc3.y + acc3.z + acc3.w;
        __syncthreads();
        // finalize: thread (rr=w, hl=lane) -> output (r0row+rr, h0+hl)
        float s = red[w][lane] + red[4 + w][lane] + red[8 + w][lane] + red[12 + w][lane];
        if (edge) s += b1[h0 + lane];
        Out[(r0row + w) * HH + h0 + lane] = (_Float16)s;
        __syncthreads();                 // red consumed before next pass writes
    }
}

// ---------------------------------------------------------------------------
// k_pairs: 32x32 tile / block, 256 blocks (1/CU), 4x4 register blocking.
// fp16 LDS tiles; chunk-XOR swizzle pos(r,cc) = r*256 + ((cc ^ (r>>2))<<3):
//  - compute b128 reads: fixed cc across lanes -> slots (cc^q) distinct mod 8
//    -> 8 non-overlapping 4-bank groups x 8-lane broadcast = bandwidth floor.
// relu(a+c) packed fp16, fp32 accumulate via v_dot2_f32_f16.
// ---------------------------------------------------------------------------
#define CT 8192     // C-tile base (halves)
#define WT 16384    // w2 base (halves)

__device__ inline float dot8(h8 w, h8 a, h8 c, float acc) {
    h8 s = a + c;
    s = __builtin_elementwise_max(s, (h8)(_Float16)0.f);
    union { h8 v; h2 p[4]; } su, wu;
    su.v = s; wu.v = w;
    acc = __builtin_amdgcn_fdot2(su.p[0], wu.p[0], acc, false);
    acc = __builtin_amdgcn_fdot2(su.p[1], wu.p[1], acc, false);
    acc = __builtin_amdgcn_fdot2(su.p[2], wu.p[2], acc, false);
    acc = __builtin_amdgcn_fdot2(su.p[3], wu.p[3], acc, false);
    return acc;
}

__global__ __launch_bounds__(256) void k_pairs(
    const _Float16* __restrict__ A, const _Float16* __restrict__ C,
    const float* __restrict__ W2, const float* __restrict__ b2,
    float* __restrict__ out)
{
    __shared__ _Float16 lds[WT + 256];     // 33.3 KB
    const int t  = threadIdx.x;
    const int bx = blockIdx.x;
    const int tn0 = (bx >> 4) * 32;
    const int tm0 = (bx & 15) * 32;

    lds[WT + t] = (_Float16)W2[t];
    #pragma unroll
    for (int q = 0; q < 8; ++q) {
        int g   = q * 256 + t;             // 0..2047
        int row = g >> 5, cc = g & 31, r = row & 31;
        int dst = (row < 32 ? 0 : CT) + r * 256 + ((cc ^ (r >> 2)) << 3);
        const _Float16* src = (row < 32) ? A + (tn0 + r) * HH + cc * 8
                                         : C + (tm0 + r) * HH + cc * 8;
        *(h8*)&lds[dst] = *(const h8*)src;
    }
    __syncthreads();

    const int w  = t >> 6, lane = t & 63;
    const int qa = lane & 7,  ra = 4 * qa;   // A rows ra..ra+3 ((ra+i)>>2 == qa)
    const int qc = lane >> 3, rc = 4 * qc;   // C rows rc..rc+3
    const int h0 = w * 64;

    float acc[4][4];
    #pragma unroll
    for (int i = 0; i < 4; ++i)
        #pragma unroll
        for (int j = 0; j < 4; ++j) acc[i][j] = 0.f;

    #pragma unroll
    for (int hh = 0; hh < 64; hh += 8) {
        int h  = h0 + hh;
        int cc = h >> 3;
        int sa = (cc ^ qa) << 3;
        int sc = (cc ^ qc) << 3;
        h8 wv = *(const h8*)&lds[WT + h];
        h8 av[4], cv[4];
        #pragma unroll
        for (int i = 0; i < 4; ++i) av[i] = *(const h8*)&lds[(ra + i) * 256 + sa];
        #pragma unroll
        for (int j = 0; j < 4; ++j) cv[j] = *(const h8*)&lds[CT + (rc + j) * 256 + sc];
        #pragma unroll
        for (int i = 0; i < 4; ++i)
            #pragma unroll
            for (int j = 0; j < 4; ++j)
                acc[i][j] = dot8(wv, av[i], cv[j], acc[i][j]);
    }

    // cross-wave reduce: float rows of 36 (9 chunks) -> b128 stores/reads at
    // the LDS bandwidth floor. red region reuses tile space (w2 untouched).
    __syncthreads();
    float* red = (float*)lds;              // [w][32 rows][36], 18.4 KB
    #pragma unroll
    for (int i = 0; i < 4; ++i) {
        float4 f;
        f.x = acc[i][0]; f.y = acc[i][1]; f.z = acc[i][2]; f.w = acc[i][3];
        *(float4*)&red[w * 1152 + (ra + i) * 36 + rc] = f;
    }
    __syncthreads();

    const int rr = t >> 3;                 // 0..31
    const int c4 = (t & 7) * 4;            // 0,4,...,28
    v4f s = *(const v4f*)&red[rr * 36 + c4];
    s += *(const v4f*)&red[1152 + rr * 36 + c4];
    s += *(const v4f*)&red[2304 + rr * 36 + c4];
    s += *(const v4f*)&red[3456 + rr * 36 + c4];
    const float b2v = b2[0];
    float4 o;
    float* op = &o.x;
    #pragma unroll
    for (int k = 0; k < 4; ++k) {
        float logit = s[k] + b2v;
        float p = 1.0f / (1.0f + __expf(-logit));
        op[k] = fminf(fmaxf(p, 1e-6f), 1.0f - 1e-6f);
    }
    *(float4*)&out[(tn0 + rr) * MM + tm0 + c4] = o;
}

extern "C" void kernel_launch(void* const* d_in, const int* in_sizes, int n_in,
                              void* d_out, int out_size, void* d_ws, size_t ws_size,
                              hipStream_t stream)
{
    const float* X  = (const float*)d_in[0];
    const int*   V  = (const int*)d_in[1];
    const int*   E  = (const int*)d_in[2];
    const float* W1 = (const float*)d_in[3];
    const float* b1 = (const float*)d_in[4];
    const float* W2 = (const float*)d_in[5];
    const float* b2 = (const float*)d_in[6];

    _Float16* A = (_Float16*)d_ws;
    _Float16* C = A + NN * HH;
    float* out  = (float*)d_out;
    int ninc    = in_sizes[1];   // 8192

    k_stage<<<256, 256, 0, stream>>>(X, V, E, W1, b1, A, C, ninc);
    k_pairs<<<256, 256, 0, stream>>>(A, C, W2, b2, out);
}